// Round 12
// baseline (231.497 us; speedup 1.0000x reference)
//
#include <hip/hip_runtime.h>

#define NB 4
#define NN 1024
#define CC 64
#define BPB (NN / 4)   // gemm blocks per batch = 256
#define ROWS 2         // adjacent rows per bcast block, written SEQUENTIALLY

typedef float f4_native __attribute__((ext_vector_type(4)));

// Kernel 1: per 4-row block:
//   yc[b,n,o] = sum_c x[b,n,c]*W0[o,c]
//   yr[b,n,o] = sum_c x[b,n,c]*W1[o,c]
//   partials[blk,c] = sum over the block's 4 rows of x[.,c]
__global__ void k_gemm(const float* __restrict__ x, const float* __restrict__ W0,
                       const float* __restrict__ W1,
                       float* __restrict__ yc, float* __restrict__ yr,
                       float* __restrict__ partials) {
    __shared__ float sW0[64][65];   // +1 pad: stride-64 col reads would be 32-way bank conflict
    __shared__ float sW1[64][65];
    __shared__ float sX[4][64];
    const int t = threadIdx.x;
    const int b = blockIdx.x / BPB;
    const int n0 = (blockIdx.x % BPB) * 4;
    for (int idx = t; idx < 64 * 64; idx += 256) {
        sW0[idx >> 6][idx & 63] = W0[idx];
        sW1[idx >> 6][idx & 63] = W1[idx];
    }
    const int o = t & 63, r = t >> 6;
    sX[r][o] = x[((size_t)(b * NN + n0 + r)) * CC + o];
    __syncthreads();
    float a0 = 0.f, a1 = 0.f;
    #pragma unroll
    for (int c = 0; c < 64; ++c) {
        const float xv = sX[r][c];
        a0 += xv * sW0[o][c];
        a1 += xv * sW1[o][c];
    }
    const size_t oidx = ((size_t)(b * NN + n0 + r)) * CC + o;
    yc[oidx] = a0;
    yr[oidx] = a1;
    if (r == 0)   // threads 0..63: column partial sum of this block's 4 rows
        partials[(size_t)blockIdx.x * 64 + o] =
            sX[0][o] + sX[1][o] + sX[2][o] + sX[3][o];
}

// Kernel 2 (tiny): reduce partials per batch -> xsum, then ysb[b,o] = xsum.W2[o,:] + bias[o]
__global__ void k_ysb(const float* __restrict__ partials, const float* __restrict__ W2,
                      const float* __restrict__ bias, float* __restrict__ ysb) {
    const int b = blockIdx.x;
    const int t = threadIdx.x;
    const int c = t & 63, g = t >> 6;   // 4 groups x 64 channels
    __shared__ float sPart[4][64];
    __shared__ float sXsum[64];
    float acc = 0.f;
    const float* pb = partials + (size_t)b * BPB * 64;
    for (int blk = g; blk < BPB; blk += 4)
        acc += pb[blk * 64 + c];
    sPart[g][c] = acc;
    __syncthreads();
    if (t < 64)
        sXsum[t] = sPart[0][t] + sPart[1][t] + sPart[2][t] + sPart[3][t];
    __syncthreads();
    if (t < 64) {
        float v = bias[t];               // bias shape (64,1) -> bias[o]
        const float* w = W2 + t * CC;
        #pragma unroll 8
        for (int cc = 0; cc < CC; ++cc) v += sXsum[cc] * w[cc];
        ysb[b * CC + t] = v;
    }
}

// Kernel 3: out[b,i,j,:] = yc[b,j,:] + yr[b,i,:] + ysb[b,:]
// R11's ping-pong chunk pipeline, but each block owns ROWS=2 ADJACENT rows
// processed one-after-the-other: one contiguous in-order 128 KB write stream
// per block, grid 2048 (all resident) -> half the concurrent HBM write
// streams, 2x the sequential run length. Store pattern within a row is
// byte-identical to R11. (Ledger: per-instr/16KB row interleave = R5/R7/R9/R10
// all lost; run length is the surviving hypothesis.)
__global__ void k_bcast(const float4* __restrict__ yc4, const float4* __restrict__ yr4,
                        const float4* __restrict__ ysb4, float4* __restrict__ out4) {
    const int t = threadIdx.x;
    const int o4 = t & 15;
    const int b = blockIdx.x / (NN / ROWS);
    const int i0 = (blockIdx.x % (NN / ROWS)) * ROWS;
    const float4 ys = ysb4[b * 16 + o4];
    const float4* ycb = yc4 + (size_t)b * NN * 16;

#define STORE_CHUNK(REGS, c, yrv, ob)                                        \
    do {                                                                     \
        float4* obc = (ob) + (c) * 1024;                                     \
        _Pragma("unroll")                                                    \
        for (int s = 0; s < 4; ++s) {                                        \
            float4 w;                                                        \
            w.x = REGS[s].x + yrv.x; w.y = REGS[s].y + yrv.y;                \
            w.z = REGS[s].z + yrv.z; w.w = REGS[s].w + yrv.w;                \
            __builtin_nontemporal_store(*(const f4_native*)&w,               \
                                        (f4_native*)&obc[t + 256 * s]);      \
        }                                                                    \
    } while (0)
#define PREFETCH(REGS, c)                                                    \
    do {                                                                     \
        const float4* src = ycb + (c) * 1024;                                \
        _Pragma("unroll")                                                    \
        for (int s = 0; s < 4; ++s) REGS[s] = src[t + 256 * s];              \
    } while (0)

    float4 sa[4], sb[4];
    for (int rr = 0; rr < ROWS; ++rr) {
        const int i = i0 + rr;
        float4 yr = yr4[(size_t)(b * NN + i) * 16 + o4];
        yr.x += ys.x; yr.y += ys.y; yr.z += ys.z; yr.w += ys.w;
        float4* ob = out4 + (size_t)(b * NN + i) * (NN * 16);
        PREFETCH(sa, 0);
        #pragma unroll
        for (int c = 0; c < 16; c += 2) {
            if (c + 1 < 16) PREFETCH(sb, c + 1);
            STORE_CHUNK(sa, c, yr, ob);
            if (c + 2 < 16) PREFETCH(sa, c + 2);
            STORE_CHUNK(sb, c + 1, yr, ob);
        }
    }
#undef STORE_CHUNK
#undef PREFETCH
}

extern "C" void kernel_launch(void* const* d_in, const int* in_sizes, int n_in,
                              void* d_out, int out_size, void* d_ws, size_t ws_size,
                              hipStream_t stream) {
    const float* x    = (const float*)d_in[0];
    // d_in[1] = adj (unused by forward)
    const float* W0   = (const float*)d_in[2];
    const float* W1   = (const float*)d_in[3];
    const float* W2   = (const float*)d_in[4];
    const float* bias = (const float*)d_in[5];
    float* out = (float*)d_out;

    float* ws       = (float*)d_ws;
    float* ysb      = ws;                                   // 256 floats
    float* yc       = ws + 256;                             // 262144 floats
    float* yr       = yc + NB * NN * CC;                    // 262144 floats
    float* partials = yr + NB * NN * CC;                    // 1024*64 = 65536 floats

    k_gemm<<<NB * BPB, 256, 0, stream>>>(x, W0, W1, yc, yr, partials);
    k_ysb<<<NB, 256, 0, stream>>>(partials, W2, bias, ysb);
    k_bcast<<<NB * (NN / ROWS), 256, 0, stream>>>((const float4*)yc, (const float4*)yr,
                                                  (const float4*)ysb, (float4*)out);
}

// Round 14
// 207.086 us; speedup vs baseline: 1.1179x; 1.1179x over previous
//
#include <hip/hip_runtime.h>

#define NB 4
#define NN 1024
#define CC 64
#define BPB (NN / 4)   // gemm blocks per batch = 256

typedef float f4_native __attribute__((ext_vector_type(4)));

// Kernel 1: per 4-row block:
//   yc[b,n,o] = sum_c x[b,n,c]*W0[o,c]
//   yr[b,n,o] = sum_c x[b,n,c]*W1[o,c]
//   partials[blk,c] = sum over the block's 4 rows of x[.,c]
__global__ void k_gemm(const float* __restrict__ x, const float* __restrict__ W0,
                       const float* __restrict__ W1,
                       float* __restrict__ yc, float* __restrict__ yr,
                       float* __restrict__ partials) {
    __shared__ float sW0[64][65];   // +1 pad: stride-64 col reads would be 32-way bank conflict
    __shared__ float sW1[64][65];
    __shared__ float sX[4][64];
    const int t = threadIdx.x;
    const int b = blockIdx.x / BPB;
    const int n0 = (blockIdx.x % BPB) * 4;
    for (int idx = t; idx < 64 * 64; idx += 256) {
        sW0[idx >> 6][idx & 63] = W0[idx];
        sW1[idx >> 6][idx & 63] = W1[idx];
    }
    const int o = t & 63, r = t >> 6;
    sX[r][o] = x[((size_t)(b * NN + n0 + r)) * CC + o];
    __syncthreads();
    float a0 = 0.f, a1 = 0.f;
    #pragma unroll
    for (int c = 0; c < 64; ++c) {
        const float xv = sX[r][c];
        a0 += xv * sW0[o][c];
        a1 += xv * sW1[o][c];
    }
    const size_t oidx = ((size_t)(b * NN + n0 + r)) * CC + o;
    yc[oidx] = a0;
    yr[oidx] = a1;
    if (r == 0)   // threads 0..63: column partial sum of this block's 4 rows
        partials[(size_t)blockIdx.x * 64 + o] =
            sX[0][o] + sX[1][o] + sX[2][o] + sX[3][o];
}

// Kernel 2 (tiny): reduce partials per batch -> xsum, then ysb[b,o] = xsum.W2[o,:] + bias[o]
__global__ void k_ysb(const float* __restrict__ partials, const float* __restrict__ W2,
                      const float* __restrict__ bias, float* __restrict__ ysb) {
    const int b = blockIdx.x;
    const int t = threadIdx.x;
    const int c = t & 63, g = t >> 6;   // 4 groups x 64 channels
    __shared__ float sPart[4][64];
    __shared__ float sXsum[64];
    float acc = 0.f;
    const float* pb = partials + (size_t)b * BPB * 64;
    for (int blk = g; blk < BPB; blk += 4)
        acc += pb[blk * 64 + c];
    sPart[g][c] = acc;
    __syncthreads();
    if (t < 64)
        sXsum[t] = sPart[0][t] + sPart[1][t] + sPart[2][t] + sPart[3][t];
    __syncthreads();
    if (t < 64) {
        float v = bias[t];               // bias shape (64,1) -> bias[o]
        const float* w = W2 + t * CC;
        #pragma unroll 8
        for (int cc = 0; cc < CC; ++cc) v += sXsum[cc] * w[cc];
        ysb[b * CC + t] = v;
    }
}

// Kernel 3: out[b,i,j,:] = yc[b,j,:] + yr[b,i,:] + ysb[b,:]
// R11 geometry exactly (1 row/block, 4096 blocks, sequential 64 KB NT stream,
// 16 chunks x 4 float4/thread). ONE variable vs R11: prefetch depth 2 via
// THREE rotating register sets -> a chunk's loads are issued 12 VMEM ops
// (2 chunks) before its stores, so the vmcnt wait tolerates all intervening
// stores + next loads and load-return latency is fully overlapped.
__global__ void k_bcast(const float4* __restrict__ yc4, const float4* __restrict__ yr4,
                        const float4* __restrict__ ysb4, float4* __restrict__ out4) {
    const int t = threadIdx.x;
    const int o4 = t & 15;
    const int b = blockIdx.x >> 10;      // / NN
    const int i = blockIdx.x & (NN - 1);
    float4 yr = yr4[(size_t)(b * NN + i) * 16 + o4];
    const float4 ys = ysb4[b * 16 + o4];
    yr.x += ys.x; yr.y += ys.y; yr.z += ys.z; yr.w += ys.w;
    const float4* ycb = yc4 + (size_t)b * NN * 16;
    float4* ob = out4 + (size_t)(b * NN + i) * (NN * 16);

#define PREFETCH(REGS, c)                                                    \
    do {                                                                     \
        const float4* src = ycb + (c) * 1024;                                \
        _Pragma("unroll")                                                    \
        for (int s = 0; s < 4; ++s) REGS[s] = src[t + 256 * s];              \
    } while (0)
#define STORE_CHUNK(REGS, c)                                                 \
    do {                                                                     \
        float4* obc = ob + (c) * 1024;                                       \
        _Pragma("unroll")                                                    \
        for (int s = 0; s < 4; ++s) {                                        \
            float4 w;                                                        \
            w.x = REGS[s].x + yr.x; w.y = REGS[s].y + yr.y;                  \
            w.z = REGS[s].z + yr.z; w.w = REGS[s].w + yr.w;                  \
            __builtin_nontemporal_store(*(const f4_native*)&w,               \
                                        (f4_native*)&obc[t + 256 * s]);      \
        }                                                                    \
    } while (0)
// STEP: prefetch chunk (c+2) into PRE, then store chunk c from CUR.
#define STEP(CUR, PRE, c)                                                    \
    do {                                                                     \
        if ((c) + 2 < 16) PREFETCH(PRE, (c) + 2);                            \
        STORE_CHUNK(CUR, c);                                                 \
    } while (0)

    float4 r0[4], r1[4], r2[4];
    PREFETCH(r0, 0);
    PREFETCH(r1, 1);
    STEP(r0, r2, 0);   STEP(r1, r0, 1);   STEP(r2, r1, 2);   STEP(r0, r2, 3);
    STEP(r1, r0, 4);   STEP(r2, r1, 5);   STEP(r0, r2, 6);   STEP(r1, r0, 7);
    STEP(r2, r1, 8);   STEP(r0, r2, 9);   STEP(r1, r0, 10);  STEP(r2, r1, 11);
    STEP(r0, r2, 12);  STEP(r1, r0, 13);  STEP(r2, r1, 14);  STEP(r0, r2, 15);
#undef STEP
#undef STORE_CHUNK
#undef PREFETCH
}

extern "C" void kernel_launch(void* const* d_in, const int* in_sizes, int n_in,
                              void* d_out, int out_size, void* d_ws, size_t ws_size,
                              hipStream_t stream) {
    const float* x    = (const float*)d_in[0];
    // d_in[1] = adj (unused by forward)
    const float* W0   = (const float*)d_in[2];
    const float* W1   = (const float*)d_in[3];
    const float* W2   = (const float*)d_in[4];
    const float* bias = (const float*)d_in[5];
    float* out = (float*)d_out;

    float* ws       = (float*)d_ws;
    float* ysb      = ws;                                   // 256 floats
    float* yc       = ws + 256;                             // 262144 floats
    float* yr       = yc + NB * NN * CC;                    // 262144 floats
    float* partials = yr + NB * NN * CC;                    // 1024*64 = 65536 floats

    k_gemm<<<NB * BPB, 256, 0, stream>>>(x, W0, W1, yc, yr, partials);
    k_ysb<<<NB, 256, 0, stream>>>(partials, W2, bias, ysb);
    k_bcast<<<NB * NN, 256, 0, stream>>>((const float4*)yc, (const float4*)yr,
                                         (const float4*)ysb, (float4*)out);
}

// Round 15
// 207.079 us; speedup vs baseline: 1.1179x; 1.0000x over previous
//
#include <hip/hip_runtime.h>

#define NB 4
#define NN 1024
#define CC 64
#define BPB (NN / 4)   // gemm blocks per batch = 256

typedef float f4_native __attribute__((ext_vector_type(4)));

// Kernel 1: per 4-row block:
//   yc[b,n,o] = sum_c x[b,n,c]*W0[o,c]
//   yr[b,n,o] = sum_c x[b,n,c]*W1[o,c]
//   partials[blk,c] = sum over the block's 4 rows of x[.,c]
__global__ void k_gemm(const float* __restrict__ x, const float* __restrict__ W0,
                       const float* __restrict__ W1,
                       float* __restrict__ yc, float* __restrict__ yr,
                       float* __restrict__ partials) {
    __shared__ float sW0[64][65];   // +1 pad: stride-64 col reads would be 32-way bank conflict
    __shared__ float sW1[64][65];
    __shared__ float sX[4][64];
    const int t = threadIdx.x;
    const int b = blockIdx.x / BPB;
    const int n0 = (blockIdx.x % BPB) * 4;
    for (int idx = t; idx < 64 * 64; idx += 256) {
        sW0[idx >> 6][idx & 63] = W0[idx];
        sW1[idx >> 6][idx & 63] = W1[idx];
    }
    const int o = t & 63, r = t >> 6;
    sX[r][o] = x[((size_t)(b * NN + n0 + r)) * CC + o];
    __syncthreads();
    float a0 = 0.f, a1 = 0.f;
    #pragma unroll
    for (int c = 0; c < 64; ++c) {
        const float xv = sX[r][c];
        a0 += xv * sW0[o][c];
        a1 += xv * sW1[o][c];
    }
    const size_t oidx = ((size_t)(b * NN + n0 + r)) * CC + o;
    yc[oidx] = a0;
    yr[oidx] = a1;
    if (r == 0)   // threads 0..63: column partial sum of this block's 4 rows
        partials[(size_t)blockIdx.x * 64 + o] =
            sX[0][o] + sX[1][o] + sX[2][o] + sX[3][o];
}

// Kernel 2 (tiny): reduce partials per batch -> xsum, then ysb[b,o] = xsum.W2[o,:] + bias[o]
__global__ void k_ysb(const float* __restrict__ partials, const float* __restrict__ W2,
                      const float* __restrict__ bias, float* __restrict__ ysb) {
    const int b = blockIdx.x;
    const int t = threadIdx.x;
    const int c = t & 63, g = t >> 6;   // 4 groups x 64 channels
    __shared__ float sPart[4][64];
    __shared__ float sXsum[64];
    float acc = 0.f;
    const float* pb = partials + (size_t)b * BPB * 64;
    for (int blk = g; blk < BPB; blk += 4)
        acc += pb[blk * 64 + c];
    sPart[g][c] = acc;
    __syncthreads();
    if (t < 64)
        sXsum[t] = sPart[0][t] + sPart[1][t] + sPart[2][t] + sPart[3][t];
    __syncthreads();
    if (t < 64) {
        float v = bias[t];               // bias shape (64,1) -> bias[o]
        const float* w = W2 + t * CC;
        #pragma unroll 8
        for (int cc = 0; cc < CC; ++cc) v += sXsum[cc] * w[cc];
        ysb[b * CC + t] = v;
    }
}

// Kernel 3: out[b,i,j,:] = yc[b,j,:] + yr[b,i,:] + ysb[b,:]
// R14 structure, prefetch depth 3 (FOUR rotating register sets): a chunk's
// loads are issued 24 VMEM ops before its stores in the in-order vmcnt queue,
// so the pre-store wait tolerates 3 chunks of newer loads + older stores and
// yc load-return latency is fully hidden. (Depth 1->2 gained 9+5.5 µs.)
__global__ void k_bcast(const float4* __restrict__ yc4, const float4* __restrict__ yr4,
                        const float4* __restrict__ ysb4, float4* __restrict__ out4) {
    const int t = threadIdx.x;
    const int o4 = t & 15;
    const int b = blockIdx.x >> 10;      // / NN
    const int i = blockIdx.x & (NN - 1);
    float4 yr = yr4[(size_t)(b * NN + i) * 16 + o4];
    const float4 ys = ysb4[b * 16 + o4];
    yr.x += ys.x; yr.y += ys.y; yr.z += ys.z; yr.w += ys.w;
    const float4* ycb = yc4 + (size_t)b * NN * 16;
    float4* ob = out4 + (size_t)(b * NN + i) * (NN * 16);

#define PREFETCH(REGS, c)                                                    \
    do {                                                                     \
        const float4* src = ycb + (c) * 1024;                                \
        _Pragma("unroll")                                                    \
        for (int s = 0; s < 4; ++s) REGS[s] = src[t + 256 * s];              \
    } while (0)
#define STORE_CHUNK(REGS, c)                                                 \
    do {                                                                     \
        float4* obc = ob + (c) * 1024;                                       \
        _Pragma("unroll")                                                    \
        for (int s = 0; s < 4; ++s) {                                        \
            float4 w;                                                        \
            w.x = REGS[s].x + yr.x; w.y = REGS[s].y + yr.y;                  \
            w.z = REGS[s].z + yr.z; w.w = REGS[s].w + yr.w;                  \
            __builtin_nontemporal_store(*(const f4_native*)&w,               \
                                        (f4_native*)&obc[t + 256 * s]);      \
        }                                                                    \
    } while (0)
// STEP: prefetch chunk (c+3) into PRE, then store chunk c from CUR.
#define STEP(CUR, PRE, c)                                                    \
    do {                                                                     \
        if ((c) + 3 < 16) PREFETCH(PRE, (c) + 3);                            \
        STORE_CHUNK(CUR, c);                                                 \
    } while (0)

    float4 r0[4], r1[4], r2[4], r3[4];
    PREFETCH(r0, 0);
    PREFETCH(r1, 1);
    PREFETCH(r2, 2);
    STEP(r0, r3, 0);   STEP(r1, r0, 1);   STEP(r2, r1, 2);   STEP(r3, r2, 3);
    STEP(r0, r3, 4);   STEP(r1, r0, 5);   STEP(r2, r1, 6);   STEP(r3, r2, 7);
    STEP(r0, r3, 8);   STEP(r1, r0, 9);   STEP(r2, r1, 10);  STEP(r3, r2, 11);
    STEP(r0, r3, 12);  STEP(r1, r0, 13);  STEP(r2, r1, 14);  STEP(r3, r2, 15);
#undef STEP
#undef STORE_CHUNK
#undef PREFETCH
}

extern "C" void kernel_launch(void* const* d_in, const int* in_sizes, int n_in,
                              void* d_out, int out_size, void* d_ws, size_t ws_size,
                              hipStream_t stream) {
    const float* x    = (const float*)d_in[0];
    // d_in[1] = adj (unused by forward)
    const float* W0   = (const float*)d_in[2];
    const float* W1   = (const float*)d_in[3];
    const float* W2   = (const float*)d_in[4];
    const float* bias = (const float*)d_in[5];
    float* out = (float*)d_out;

    float* ws       = (float*)d_ws;
    float* ysb      = ws;                                   // 256 floats
    float* yc       = ws + 256;                             // 262144 floats
    float* yr       = yc + NB * NN * CC;                    // 262144 floats
    float* partials = yr + NB * NN * CC;                    // 1024*64 = 65536 floats

    k_gemm<<<NB * BPB, 256, 0, stream>>>(x, W0, W1, yc, yr, partials);
    k_ysb<<<NB, 256, 0, stream>>>(partials, W2, bias, ysb);
    k_bcast<<<NB * NN, 256, 0, stream>>>((const float4*)yc, (const float4*)yr,
                                         (const float4*)ysb, (float4*)out);
}